// Round 8
// baseline (529.373 us; speedup 1.0000x reference)
//
#include <hip/hip_runtime.h>

// Residual VQ, Q=4 stages. R14 = R13 (balanced R7 tile: BPTS=64, acc[8][16],
// (256,2) clean 120-reg alloc, 514us) + occupancy fix: R13's LDS was 53760 B,
// missing the 3-blocks/CU threshold (163840/3 = 53333 B) by 427 bytes -> 2
// blocks/CU, 39% idle at barriers. R14 deletes s_csq (2 KB): each thread loads
// its 16 striped -csq/2 values from global into registers ONCE before the
// q-loop (bit-identical; also drops 4 LDS b128 init-reads per thread/stage).
// LDS 51456 B -> 3 blocks/CU = 12 waves/CU. All numerics = R13 bit-exact path.
// (Resubmission: previous round failed with a container/broker infra error,
// no kernel verdict.)
//
// d_out: quantized [8,64,128,128] (8388608 f32) | indices as float
//        [8,128,128,4] (524288) | commit_loss [4].
// d_ws: cbS [64][512] bank-striped transposed codebook + csqS [512] (striped -csq/2).

#define NPTS   131072
#define CH     64
#define KCODE  512
#define NQ     4
#define HW     16384
#define BPTS   64        // points per block
#define BTHR   256       // threads per block (4 waves)
#define CCH    8         // channels per chunk
#define NCHK   8         // chunks per stage (CH / CCH)

__device__ __forceinline__ void load_lds16(const float* g, float* l) {
    __builtin_amdgcn_global_load_lds(
        (const __attribute__((address_space(1))) void*)g,
        (__attribute__((address_space(3))) void*)l, 16, 0, 0);
}

// cbS[c*512 + pos] = cb[k*64 + c], pos(k) = i*128 + cg*4 + j for k = cg*16+i*4+j
__global__ void prep_cbS(const float* __restrict__ cb, float* __restrict__ cbS) {
    int g = blockIdx.x * 256 + threadIdx.x;   // 0..32767
    int c = g >> 9, pos = g & 511;
    int i = pos >> 7, cg = (pos >> 2) & 31, j = pos & 3;
    int k = cg * 16 + i * 4 + j;
    cbS[g] = cb[k * CH + c];
}

// csqS[pos(k)] = -0.5 * ||cb[k]||^2, same striped pos(k) mapping as cbS.
__global__ void prep_csq(const float* __restrict__ cb, float* __restrict__ csqS) {
    int k = blockIdx.x * 256 + threadIdx.x;
    if (k < KCODE) {
        const float4* row = (const float4*)(cb + (size_t)k * CH);
        float a0 = 0.f, a1 = 0.f, a2 = 0.f, a3 = 0.f;
#pragma unroll
        for (int j = 0; j < CH / 4; ++j) {
            float4 v = row[j];
            a0 = fmaf(v.x, v.x, a0); a1 = fmaf(v.y, v.y, a1);
            a2 = fmaf(v.z, v.z, a2); a3 = fmaf(v.w, v.w, a3);
        }
        float s = (a0 + a1) + (a2 + a3);
        int cg = k >> 4, i = (k & 15) >> 2, j = k & 3;
        csqS[i * 128 + cg * 4 + j] = -0.5f * s;
    }
}

__global__ __launch_bounds__(BTHR, 2) void rvq_main(
    const float* __restrict__ x, const float* __restrict__ cb,
    const float* __restrict__ cbS, const float* __restrict__ csq_g,
    float* __restrict__ out_quant, float* __restrict__ out_idx,
    float* __restrict__ out_loss)
{
    __shared__ __align__(16) float s_res[CH * BPTS];        // 16 KB residual [c][p]
    __shared__ __align__(16) float s_buf[2][CCH * KCODE];   // 2 x 16 KB chunk buffers
    __shared__ int   s_bidx[BPTS];                          // 256 B
    __shared__ int   s_idx4[BPTS * NQ];                     // 1 KB
    __shared__ float s_ls[4 * BPTS];                        // 1 KB
    // total 51456 B -> 3 blocks/CU

    const int tid  = threadIdx.x;
    const int lane = tid & 63;
    const int w    = tid >> 6;
    const int cg   = tid & 31;   // 16 codes: k = cg*16 + n
    const int pg   = tid >> 5;   // 8 points: p = pg*8 .. pg*8+7

    const int n0  = blockIdx.x * BPTS;   // block never straddles batch index
    const int b   = n0 >> 14;
    const int hw0 = n0 & (HW - 1);
    const float* xbase = x + (size_t)b * CH * HW + hw0;

    // ---- prefetch stage-0 chunk 0 into buf[0] (overlaps x-tile load) ----
#pragma unroll
    for (int r = 0; r < 4; ++r) {
        int off = (w * 4 + r) * 256;
        load_lds16(cbS + off + lane * 4, &s_buf[0][off]);
    }

    // ---- this thread's 16 striped -csq/2 values -> registers (once) ----
    float csqr[16];
    {
        const float* cqp = csq_g + cg * 4;
#pragma unroll
        for (int i = 0; i < 4; ++i) {
            float4 iv = *(const float4*)(cqp + i * 128);
            csqr[i * 4 + 0] = iv.x; csqr[i * 4 + 1] = iv.y;
            csqr[i * 4 + 2] = iv.z; csqr[i * 4 + 3] = iv.w;
        }
    }

    // ---- x tile -> s_res ----
    for (int j = tid; j < CH * BPTS / 4; j += BTHR) {
        int c = j >> 4, p4 = j & 15;
        *(float4*)&s_res[c * BPTS + p4 * 4] =
            *(const float4*)(xbase + (size_t)c * HW + p4 * 4);
    }
    __syncthreads();   // s_res visible, buf[0] drained

    for (int q = 0; q < NQ; ++q) {
        // ---- acc init = -csq/2 (from registers) ----
        float acc[8][16];
#pragma unroll
        for (int n = 0; n < 16; ++n) {
            float v = csqr[n];
#pragma unroll
            for (int p = 0; p < 8; ++p) acc[p][n] = v;
        }

        // ---- GEMM: 8 chunks x 8 channels, double-buffered ----
        for (int chk = 0; chk < NCHK; ++chk) {
            // prefetch next chunk (chunk 0 of next stage on wrap) into the
            // other buffer; it has the whole current chunk's compute to land.
            if (!(q == NQ - 1 && chk == NCHK - 1)) {
                const int nchk = (chk + 1 < NCHK) ? chk + 1 : 0;
                const float* src = cbS + nchk * (CCH * KCODE);
                float* dst = s_buf[(chk + 1) & 1];
#pragma unroll
                for (int r = 0; r < 4; ++r) {
                    int off = (w * 4 + r) * 256;
                    load_lds16(src + off + lane * 4, dst + off);
                }
            }

            const float* bufp = s_buf[chk & 1];
#pragma unroll 2
            for (int c = 0; c < CCH; ++c) {
                const float* ar = &s_res[(chk * CCH + c) * BPTS + pg * 8];
                float4 a0 = *(const float4*)(ar + 0);
                float4 a1 = *(const float4*)(ar + 4);
                float av[8] = {a0.x, a0.y, a0.z, a0.w, a1.x, a1.y, a1.z, a1.w};
                const float* br = &bufp[c * KCODE + cg * 4];
#pragma unroll
                for (int nb = 0; nb < 4; ++nb) {
                    float4 bq = *(const float4*)(br + nb * 128);
#pragma unroll
                    for (int p = 0; p < 8; ++p) {
                        acc[p][nb * 4 + 0] = fmaf(av[p], bq.x, acc[p][nb * 4 + 0]);
                        acc[p][nb * 4 + 1] = fmaf(av[p], bq.y, acc[p][nb * 4 + 1]);
                        acc[p][nb * 4 + 2] = fmaf(av[p], bq.z, acc[p][nb * 4 + 2]);
                        acc[p][nb * 4 + 3] = fmaf(av[p], bq.w, acc[p][nb * 4 + 3]);
                    }
                }
            }
            __syncthreads();   // all waves done with buf[chk&1]; prefetch drained
        }

        // ---- per-thread argmax over own 16 codes (ascending k, strict >) ----
        float bd[8]; int bi[8];
#pragma unroll
        for (int p = 0; p < 8; ++p) {
            float B = acc[p][0]; int I = cg * 16;
#pragma unroll
            for (int n = 1; n < 16; ++n)
                if (acc[p][n] > B) { B = acc[p][n]; I = cg * 16 + n; }
            bd[p] = B; bi[p] = I;
        }

        // ---- half-wave butterfly merge across the 32 cg-lanes (in-register) ----
#pragma unroll
        for (int m = 1; m <= 16; m <<= 1) {
#pragma unroll
            for (int p = 0; p < 8; ++p) {
                float oB = __shfl_xor(bd[p], m, 64);
                int   oI = __shfl_xor(bi[p], m, 64);
                if (oB > bd[p] || (oB == bd[p] && oI < bi[p])) {
                    bd[p] = oB; bi[p] = oI;
                }
            }
        }
        if (cg == 0) {
#pragma unroll
            for (int p = 0; p < 8; ++p) {
                s_bidx[pg * 8 + p] = bi[p];
                s_idx4[(pg * 8 + p) * 4 + q] = bi[p];
            }
        }
        __syncthreads();   // s_bidx visible

        // ---- residual update (exact r' = r - c) + loss partials ----
        {
            const int p  = tid & 63;
            const int cq = tid >> 6;   // 16-channel quarter
            int bix = s_bidx[p];
            const float4* crow = (const float4*)(cb + (size_t)bix * CH + cq * 16);
            float l0 = 0.f, l1 = 0.f, l2 = 0.f, l3 = 0.f;
#pragma unroll
            for (int i = 0; i < 4; ++i) {
                float4 v = crow[i];
                int c = cq * 16 + i * 4;
                float r0 = s_res[(c + 0) * BPTS + p] - v.x;
                float r1 = s_res[(c + 1) * BPTS + p] - v.y;
                float r2 = s_res[(c + 2) * BPTS + p] - v.z;
                float r3 = s_res[(c + 3) * BPTS + p] - v.w;
                s_res[(c + 0) * BPTS + p] = r0;
                s_res[(c + 1) * BPTS + p] = r1;
                s_res[(c + 2) * BPTS + p] = r2;
                s_res[(c + 3) * BPTS + p] = r3;
                l0 = fmaf(r0, r0, l0); l1 = fmaf(r1, r1, l1);
                l2 = fmaf(r2, r2, l2); l3 = fmaf(r3, r3, l3);
            }
            s_ls[cq * BPTS + p] = (l0 + l1) + (l2 + l3);
        }
        __syncthreads();   // s_res + s_ls visible

        // ---- commit-loss reduce for this stage (wave 0; q is uniform) ----
        if (w == 0) {
            float v = (s_ls[0 * BPTS + lane] + s_ls[1 * BPTS + lane]) +
                      (s_ls[2 * BPTS + lane] + s_ls[3 * BPTS + lane]);
            for (int off = 32; off > 0; off >>= 1) v += __shfl_down(v, off, 64);
            if (lane == 0)
                atomicAdd(&out_loss[q], v * (1.0f / 8388608.0f));  // /(NPTS*CH)
        }
    }

    // ---- epilogue: quantized = sum of 4 chosen code rows (sequential order) ----
    {
        const int p  = tid & 63;
        const int cq = tid >> 6;
        int e0 = s_idx4[p * 4 + 0], e1 = s_idx4[p * 4 + 1];
        int e2 = s_idx4[p * 4 + 2], e3 = s_idx4[p * 4 + 3];
        const float4* r0 = (const float4*)(cb + (size_t)e0 * CH + cq * 16);
        const float4* r1 = (const float4*)(cb + (size_t)e1 * CH + cq * 16);
        const float4* r2 = (const float4*)(cb + (size_t)e2 * CH + cq * 16);
        const float4* r3 = (const float4*)(cb + (size_t)e3 * CH + cq * 16);
        float* ob = out_quant + (size_t)b * CH * HW + hw0;
#pragma unroll
        for (int i = 0; i < 4; ++i) {
            float4 v0 = r0[i], v1 = r1[i], v2 = r2[i], v3 = r3[i];
            float s0 = ((v0.x + v1.x) + v2.x) + v3.x;
            float s1 = ((v0.y + v1.y) + v2.y) + v3.y;
            float s2 = ((v0.z + v1.z) + v2.z) + v3.z;
            float s3 = ((v0.w + v1.w) + v2.w) + v3.w;
            int c = cq * 16 + i * 4;
            ob[(size_t)(c + 0) * HW + p] = s0;
            ob[(size_t)(c + 1) * HW + p] = s1;
            ob[(size_t)(c + 2) * HW + p] = s2;
            ob[(size_t)(c + 3) * HW + p] = s3;
        }

        // indices (wave 0; e0..e3 already in registers)
        if (tid < BPTS)
            ((float4*)out_idx)[n0 + p] =
                make_float4((float)e0, (float)e1, (float)e2, (float)e3);
    }
}

extern "C" void kernel_launch(void* const* d_in, const int* in_sizes, int n_in,
                              void* d_out, int out_size, void* d_ws, size_t ws_size,
                              hipStream_t stream) {
    const float* x  = (const float*)d_in[0];
    const float* cb = (const float*)d_in[1];
    float* out       = (float*)d_out;
    float* out_quant = out;                    // 8388608
    float* out_idx   = out + 8388608;          // 524288
    float* out_loss  = out + 8388608 + 524288; // 4

    float* cbS = (float*)d_ws;                 // 64*512 floats
    float* csq = cbS + CH * KCODE;             // 512 floats (striped -csq/2)

    hipMemsetAsync(out_loss, 0, NQ * sizeof(float), stream);
    prep_cbS<<<(CH * KCODE) / 256, 256, 0, stream>>>(cb, cbS);
    prep_csq<<<2, 256, 0, stream>>>(cb, csq);
    rvq_main<<<NPTS / BPTS, BTHR, 0, stream>>>(x, cb, cbS, csq,
                                               out_quant, out_idx, out_loss);
}

// Round 9
// 528.177 us; speedup vs baseline: 1.0023x; 1.0023x over previous
//
#include <hip/hip_runtime.h>

// Residual VQ, Q=4 stages. R15 = R14 (balanced tile acc[8][16], clean regs,
// LDS 51456 B, 511us) + occupancy fix via RAW attribute. Evidence across
// R7-R14: hipcc maps __launch_bounds__'s 2nd arg N -> amdgpu-waves-per-eu
// min = 2N, and LLVM allocates VGPRs down to that target (arg=4 -> 64 regs,
// arg=3 -> 84 regs/spills, arg=2 -> <=128 regs); measured occupancy tracks
// the same knob (~2 waves/SIMD at arg=2 regardless of LDS fitting 3 blocks).
// The desired 3-waves/SIMD target (reg cap 170, clean for our ~125-reg live
// set) is odd -> unreachable via launch_bounds. R15 uses
// __attribute__((amdgpu_waves_per_eu(3))) directly: cap 168, 3 blocks/CU
// by LDS, 12 waves/CU. All numerics = R14/R13 bit-exact passing path.
//
// d_out: quantized [8,64,128,128] (8388608 f32) | indices as float
//        [8,128,128,4] (524288) | commit_loss [4].
// d_ws: cbS [64][512] bank-striped transposed codebook + csqS [512] (striped -csq/2).

#define NPTS   131072
#define CH     64
#define KCODE  512
#define NQ     4
#define HW     16384
#define BPTS   64        // points per block
#define BTHR   256       // threads per block (4 waves)
#define CCH    8         // channels per chunk
#define NCHK   8         // chunks per stage (CH / CCH)

__device__ __forceinline__ void load_lds16(const float* g, float* l) {
    __builtin_amdgcn_global_load_lds(
        (const __attribute__((address_space(1))) void*)g,
        (__attribute__((address_space(3))) void*)l, 16, 0, 0);
}

// cbS[c*512 + pos] = cb[k*64 + c], pos(k) = i*128 + cg*4 + j for k = cg*16+i*4+j
__global__ void prep_cbS(const float* __restrict__ cb, float* __restrict__ cbS) {
    int g = blockIdx.x * 256 + threadIdx.x;   // 0..32767
    int c = g >> 9, pos = g & 511;
    int i = pos >> 7, cg = (pos >> 2) & 31, j = pos & 3;
    int k = cg * 16 + i * 4 + j;
    cbS[g] = cb[k * CH + c];
}

// csqS[pos(k)] = -0.5 * ||cb[k]||^2, same striped pos(k) mapping as cbS.
__global__ void prep_csq(const float* __restrict__ cb, float* __restrict__ csqS) {
    int k = blockIdx.x * 256 + threadIdx.x;
    if (k < KCODE) {
        const float4* row = (const float4*)(cb + (size_t)k * CH);
        float a0 = 0.f, a1 = 0.f, a2 = 0.f, a3 = 0.f;
#pragma unroll
        for (int j = 0; j < CH / 4; ++j) {
            float4 v = row[j];
            a0 = fmaf(v.x, v.x, a0); a1 = fmaf(v.y, v.y, a1);
            a2 = fmaf(v.z, v.z, a2); a3 = fmaf(v.w, v.w, a3);
        }
        float s = (a0 + a1) + (a2 + a3);
        int cg = k >> 4, i = (k & 15) >> 2, j = k & 3;
        csqS[i * 128 + cg * 4 + j] = -0.5f * s;
    }
}

__global__ __launch_bounds__(BTHR)
__attribute__((amdgpu_waves_per_eu(3))) void rvq_main(
    const float* __restrict__ x, const float* __restrict__ cb,
    const float* __restrict__ cbS, const float* __restrict__ csq_g,
    float* __restrict__ out_quant, float* __restrict__ out_idx,
    float* __restrict__ out_loss)
{
    __shared__ __align__(16) float s_res[CH * BPTS];        // 16 KB residual [c][p]
    __shared__ __align__(16) float s_buf[2][CCH * KCODE];   // 2 x 16 KB chunk buffers
    __shared__ int   s_bidx[BPTS];                          // 256 B
    __shared__ int   s_idx4[BPTS * NQ];                     // 1 KB
    __shared__ float s_ls[4 * BPTS];                        // 1 KB
    // total 51456 B -> 3 blocks/CU

    const int tid  = threadIdx.x;
    const int lane = tid & 63;
    const int w    = tid >> 6;
    const int cg   = tid & 31;   // 16 codes: k = cg*16 + n
    const int pg   = tid >> 5;   // 8 points: p = pg*8 .. pg*8+7

    const int n0  = blockIdx.x * BPTS;   // block never straddles batch index
    const int b   = n0 >> 14;
    const int hw0 = n0 & (HW - 1);
    const float* xbase = x + (size_t)b * CH * HW + hw0;

    // ---- prefetch stage-0 chunk 0 into buf[0] (overlaps x-tile load) ----
#pragma unroll
    for (int r = 0; r < 4; ++r) {
        int off = (w * 4 + r) * 256;
        load_lds16(cbS + off + lane * 4, &s_buf[0][off]);
    }

    // ---- this thread's 16 striped -csq/2 values -> registers (once) ----
    float csqr[16];
    {
        const float* cqp = csq_g + cg * 4;
#pragma unroll
        for (int i = 0; i < 4; ++i) {
            float4 iv = *(const float4*)(cqp + i * 128);
            csqr[i * 4 + 0] = iv.x; csqr[i * 4 + 1] = iv.y;
            csqr[i * 4 + 2] = iv.z; csqr[i * 4 + 3] = iv.w;
        }
    }

    // ---- x tile -> s_res ----
    for (int j = tid; j < CH * BPTS / 4; j += BTHR) {
        int c = j >> 4, p4 = j & 15;
        *(float4*)&s_res[c * BPTS + p4 * 4] =
            *(const float4*)(xbase + (size_t)c * HW + p4 * 4);
    }
    __syncthreads();   // s_res visible, buf[0] drained

    for (int q = 0; q < NQ; ++q) {
        // ---- acc init = -csq/2 (from registers) ----
        float acc[8][16];
#pragma unroll
        for (int n = 0; n < 16; ++n) {
            float v = csqr[n];
#pragma unroll
            for (int p = 0; p < 8; ++p) acc[p][n] = v;
        }

        // ---- GEMM: 8 chunks x 8 channels, double-buffered ----
        for (int chk = 0; chk < NCHK; ++chk) {
            // prefetch next chunk (chunk 0 of next stage on wrap) into the
            // other buffer; it has the whole current chunk's compute to land.
            if (!(q == NQ - 1 && chk == NCHK - 1)) {
                const int nchk = (chk + 1 < NCHK) ? chk + 1 : 0;
                const float* src = cbS + nchk * (CCH * KCODE);
                float* dst = s_buf[(chk + 1) & 1];
#pragma unroll
                for (int r = 0; r < 4; ++r) {
                    int off = (w * 4 + r) * 256;
                    load_lds16(src + off + lane * 4, dst + off);
                }
            }

            const float* bufp = s_buf[chk & 1];
#pragma unroll 2
            for (int c = 0; c < CCH; ++c) {
                const float* ar = &s_res[(chk * CCH + c) * BPTS + pg * 8];
                float4 a0 = *(const float4*)(ar + 0);
                float4 a1 = *(const float4*)(ar + 4);
                float av[8] = {a0.x, a0.y, a0.z, a0.w, a1.x, a1.y, a1.z, a1.w};
                const float* br = &bufp[c * KCODE + cg * 4];
#pragma unroll
                for (int nb = 0; nb < 4; ++nb) {
                    float4 bq = *(const float4*)(br + nb * 128);
#pragma unroll
                    for (int p = 0; p < 8; ++p) {
                        acc[p][nb * 4 + 0] = fmaf(av[p], bq.x, acc[p][nb * 4 + 0]);
                        acc[p][nb * 4 + 1] = fmaf(av[p], bq.y, acc[p][nb * 4 + 1]);
                        acc[p][nb * 4 + 2] = fmaf(av[p], bq.z, acc[p][nb * 4 + 2]);
                        acc[p][nb * 4 + 3] = fmaf(av[p], bq.w, acc[p][nb * 4 + 3]);
                    }
                }
            }
            __syncthreads();   // all waves done with buf[chk&1]; prefetch drained
        }

        // ---- per-thread argmax over own 16 codes (ascending k, strict >) ----
        float bd[8]; int bi[8];
#pragma unroll
        for (int p = 0; p < 8; ++p) {
            float B = acc[p][0]; int I = cg * 16;
#pragma unroll
            for (int n = 1; n < 16; ++n)
                if (acc[p][n] > B) { B = acc[p][n]; I = cg * 16 + n; }
            bd[p] = B; bi[p] = I;
        }

        // ---- half-wave butterfly merge across the 32 cg-lanes (in-register) ----
#pragma unroll
        for (int m = 1; m <= 16; m <<= 1) {
#pragma unroll
            for (int p = 0; p < 8; ++p) {
                float oB = __shfl_xor(bd[p], m, 64);
                int   oI = __shfl_xor(bi[p], m, 64);
                if (oB > bd[p] || (oB == bd[p] && oI < bi[p])) {
                    bd[p] = oB; bi[p] = oI;
                }
            }
        }
        if (cg == 0) {
#pragma unroll
            for (int p = 0; p < 8; ++p) {
                s_bidx[pg * 8 + p] = bi[p];
                s_idx4[(pg * 8 + p) * 4 + q] = bi[p];
            }
        }
        __syncthreads();   // s_bidx visible

        // ---- residual update (exact r' = r - c) + loss partials ----
        {
            const int p  = tid & 63;
            const int cq = tid >> 6;   // 16-channel quarter
            int bix = s_bidx[p];
            const float4* crow = (const float4*)(cb + (size_t)bix * CH + cq * 16);
            float l0 = 0.f, l1 = 0.f, l2 = 0.f, l3 = 0.f;
#pragma unroll
            for (int i = 0; i < 4; ++i) {
                float4 v = crow[i];
                int c = cq * 16 + i * 4;
                float r0 = s_res[(c + 0) * BPTS + p] - v.x;
                float r1 = s_res[(c + 1) * BPTS + p] - v.y;
                float r2 = s_res[(c + 2) * BPTS + p] - v.z;
                float r3 = s_res[(c + 3) * BPTS + p] - v.w;
                s_res[(c + 0) * BPTS + p] = r0;
                s_res[(c + 1) * BPTS + p] = r1;
                s_res[(c + 2) * BPTS + p] = r2;
                s_res[(c + 3) * BPTS + p] = r3;
                l0 = fmaf(r0, r0, l0); l1 = fmaf(r1, r1, l1);
                l2 = fmaf(r2, r2, l2); l3 = fmaf(r3, r3, l3);
            }
            s_ls[cq * BPTS + p] = (l0 + l1) + (l2 + l3);
        }
        __syncthreads();   // s_res + s_ls visible

        // ---- commit-loss reduce for this stage (wave 0; q is uniform) ----
        if (w == 0) {
            float v = (s_ls[0 * BPTS + lane] + s_ls[1 * BPTS + lane]) +
                      (s_ls[2 * BPTS + lane] + s_ls[3 * BPTS + lane]);
            for (int off = 32; off > 0; off >>= 1) v += __shfl_down(v, off, 64);
            if (lane == 0)
                atomicAdd(&out_loss[q], v * (1.0f / 8388608.0f));  // /(NPTS*CH)
        }
    }

    // ---- epilogue: quantized = sum of 4 chosen code rows (sequential order) ----
    {
        const int p  = tid & 63;
        const int cq = tid >> 6;
        int e0 = s_idx4[p * 4 + 0], e1 = s_idx4[p * 4 + 1];
        int e2 = s_idx4[p * 4 + 2], e3 = s_idx4[p * 4 + 3];
        const float4* r0 = (const float4*)(cb + (size_t)e0 * CH + cq * 16);
        const float4* r1 = (const float4*)(cb + (size_t)e1 * CH + cq * 16);
        const float4* r2 = (const float4*)(cb + (size_t)e2 * CH + cq * 16);
        const float4* r3 = (const float4*)(cb + (size_t)e3 * CH + cq * 16);
        float* ob = out_quant + (size_t)b * CH * HW + hw0;
#pragma unroll
        for (int i = 0; i < 4; ++i) {
            float4 v0 = r0[i], v1 = r1[i], v2 = r2[i], v3 = r3[i];
            float s0 = ((v0.x + v1.x) + v2.x) + v3.x;
            float s1 = ((v0.y + v1.y) + v2.y) + v3.y;
            float s2 = ((v0.z + v1.z) + v2.z) + v3.z;
            float s3 = ((v0.w + v1.w) + v2.w) + v3.w;
            int c = cq * 16 + i * 4;
            ob[(size_t)(c + 0) * HW + p] = s0;
            ob[(size_t)(c + 1) * HW + p] = s1;
            ob[(size_t)(c + 2) * HW + p] = s2;
            ob[(size_t)(c + 3) * HW + p] = s3;
        }

        // indices (wave 0; e0..e3 already in registers)
        if (tid < BPTS)
            ((float4*)out_idx)[n0 + p] =
                make_float4((float)e0, (float)e1, (float)e2, (float)e3);
    }
}

extern "C" void kernel_launch(void* const* d_in, const int* in_sizes, int n_in,
                              void* d_out, int out_size, void* d_ws, size_t ws_size,
                              hipStream_t stream) {
    const float* x  = (const float*)d_in[0];
    const float* cb = (const float*)d_in[1];
    float* out       = (float*)d_out;
    float* out_quant = out;                    // 8388608
    float* out_idx   = out + 8388608;          // 524288
    float* out_loss  = out + 8388608 + 524288; // 4

    float* cbS = (float*)d_ws;                 // 64*512 floats
    float* csq = cbS + CH * KCODE;             // 512 floats (striped -csq/2)

    hipMemsetAsync(out_loss, 0, NQ * sizeof(float), stream);
    prep_cbS<<<(CH * KCODE) / 256, 256, 0, stream>>>(cb, cbS);
    prep_csq<<<2, 256, 0, stream>>>(cb, csq);
    rvq_main<<<NPTS / BPTS, BTHR, 0, stream>>>(x, cb, cbS, csq,
                                               out_quant, out_idx, out_loss);
}